// Round 13
// baseline (335.478 us; speedup 1.0000x reference)
//
#include <hip/hip_runtime.h>
#include <cstdint>

#define NROWS 32768
#define HD    1024
#define KSEL  8192
#define LN_EPS 1e-12f
#define PD_EPS 1e-6f

typedef unsigned short u16;
typedef __bf16 bf16x8 __attribute__((ext_vector_type(8)));
typedef float  f32x16 __attribute__((ext_vector_type(16)));

__device__ inline u16 f2bf(float f) {
    union { float f; uint32_t u; } x; x.f = f;
    uint32_t r = (x.u + 0x7fffu + ((x.u >> 16) & 1u)) >> 16;
    return (u16)r;
}

__device__ inline uint2 pack4(float a, float b, float c, float d) {
    uint2 r;
    r.x = (uint32_t)f2bf(a) | ((uint32_t)f2bf(b) << 16);
    r.y = (uint32_t)f2bf(c) | ((uint32_t)f2bf(d) << 16);
    return r;
}

// ---------------- mask compaction (layout-robust) ----------------
__global__ void compact_mask_k(const uint8_t* mb, const int32_t* mi, int* idx) {
    __shared__ int cnt[1024];
    __shared__ int tmp[1024];
    __shared__ int mode_s;
    const int t = threadIdx.x;
    const int per = NROWS / 1024;      // 32
    const int base = t * per;
    int c0 = 0;
    for (int i = 0; i < per; ++i) c0 += (mb[base + i] != 0);
    tmp[t] = c0;
    __syncthreads();
    for (int off = 512; off > 0; off >>= 1) {
        if (t < off) tmp[t] += tmp[t + off];
        __syncthreads();
    }
    if (t == 0) mode_s = (tmp[0] == KSEL) ? 0 : 1;
    __syncthreads();
    const int mode = mode_s;
    int c = c0;
    if (mode) { c = 0; for (int i = 0; i < per; ++i) c += (mi[base + i] != 0); }
    cnt[t] = c;
    __syncthreads();
    for (int off = 1; off < 1024; off <<= 1) {
        int add = (t >= off) ? cnt[t - off] : 0;
        __syncthreads();
        cnt[t] += add;
        __syncthreads();
    }
    int pos = cnt[t] - c;
    for (int i = 0; i < per; ++i) {
        bool v = mode ? (mi[base + i] != 0) : (mb[base + i] != 0);
        if (v) idx[pos++] = base + i;
    }
}

// ------- gather selected rows -> bf16, fused with dense_w -> bf16 -------
__global__ void gather_conv_k(const float* __restrict__ msp, const float* __restrict__ lab,
                              const int* __restrict__ idx, const float* __restrict__ W,
                              u16* __restrict__ predsB, u16* __restrict__ labelsB,
                              u16* __restrict__ Wb) {
    const int b = blockIdx.x;
    const int t = threadIdx.x;
    if (b < KSEL) {
        const int src = idx[b];
        float4 p = *(const float4*)(msp + (size_t)src * HD + t * 4);
        float4 q = *(const float4*)(lab + (size_t)src * HD + t * 4);
        *(uint2*)(predsB  + (size_t)b * HD + t * 4) = pack4(p.x, p.y, p.z, p.w);
        *(uint2*)(labelsB + (size_t)b * HD + t * 4) = pack4(q.x, q.y, q.z, q.w);
    } else {
        const int i = ((b - KSEL) * 256 + t) * 4;   // 1024 blocks cover HD*HD
        float4 v = *(const float4*)(W + i);
        *(uint2*)(Wb + i) = pack4(v.x, v.y, v.z, v.w);
    }
}

// =======================================================================
// 256x256 tile, BK=64, 8 waves (2M x 4N), per-wave 128x64.
// ROUND-13 CHANGE: MFMA shape 16x16x32 -> 32x32x16 (halves instruction
// count: 32/tile/wave vs 64; ubench ceiling 2382 vs 2075 TF; fatter ops
// hide the 24 ds_reads under ~32cy each — r7-r12 exhausted schedule
// levers at 30-34% MfmaUtil). NT stores REVERTED (r12: WRITE_SIZE rose
// 264->350MB, no FETCH change — RFO theory dead).
// Fragments (32x32x16 bf16): A/B lane l -> row/col l&31, k=(l>>5)*8+e
// (one b128 per frag; quarter-wave slot-XOR stays 2-way/free since
// row&7 == l&7). C/D: col=l&31, row=(reg&3)+8*(reg>>2)+4*(l>>5)
// [guide m74/m101 verified]. C stores now 128B contiguous per half.
// K-loop sync unchanged from r11: all reads first, stages after, one
// counted vmcnt(4)+barrier per tile (proof in r10/r11).
// LDS 160KB: A triple (3x32KB) @0/16384/32768, B double @49152/65536.
// =======================================================================
#define STAGE(XPTR, ROWBASE, KT, I, LBASE) do {                                      \
    const int f_ = (I) * 512 + tid;                                                  \
    const int r_ = f_ >> 3;                                                          \
    const int sp_ = (f_ & 7) ^ (r_ & 7);                                             \
    const u16* g_ = (XPTR) + (size_t)((ROWBASE) + r_) * Kd + koff + (KT) * 64 + sp_ * 8; \
    __builtin_amdgcn_global_load_lds(                                                \
        (const __attribute__((address_space(1))) void*)g_,                           \
        (__attribute__((address_space(3))) void*)(lds + (LBASE) + f_ * 8), 16, 0, 0);\
} while (0)

// Shared prologue + K-loop. Uses: bid, nwg, Kd (row stride), koff, TVAL.
// Defines for epilogues: acc[4][2] (f32x16), brow,bcol,wm,wn,r5,hk,tid.
#define GEMM_PRO_AND_KLOOP(TVAL)                                                      \
    const int nx  = N >> 8;                                                           \
    int wg  = ((nwg & 7) == 0) ? ((bid & 7) * (nwg >> 3) + (bid >> 3)) : bid;         \
    const int bm = wg / nx, bn = wg % nx;                                             \
    const size_t brow = (size_t)bm << 8, bcol = (size_t)bn << 8;                      \
    const int tid = threadIdx.x;                                                      \
    const int l = tid & 63, wid = tid >> 6;                                           \
    const int wm = wid >> 2, wn = wid & 3;                                            \
    const int r5 = l & 31, hk = l >> 5;                                               \
    const int sw = l & 7;                                                             \
    f32x16 acc[4][2] = {};                                                            \
    const int arow = (wm * 128 + r5) * 64;                                            \
    const int brow2 = (wn * 64 + r5) * 64;                                            \
    /* slot elem-offsets for K-subs 0..3: ((kk*2+hk)^sw)*8 */                          \
    const int s0 = ((0 + hk) ^ sw) * 8;                                               \
    const int s1 = ((2 + hk) ^ sw) * 8;                                               \
    const int s2 = ((4 + hk) ^ sw) * 8;                                               \
    const int s3 = ((6 + hk) ^ sw) * 8;                                               \
    _Pragma("unroll")                                                                 \
    for (int i = 0; i < 4; ++i) STAGE(A,  brow, 0, i, 0);                             \
    _Pragma("unroll")                                                                 \
    for (int i = 0; i < 4; ++i) STAGE(Bt, bcol, 0, i, 49152);                         \
    _Pragma("unroll")                                                                 \
    for (int i = 0; i < 4; ++i) STAGE(A,  brow, 1, i, 16384);                         \
    asm volatile("s_waitcnt vmcnt(4)" ::: "memory");                                  \
    __builtin_amdgcn_s_barrier();                                                     \
    const int T = (TVAL);                                                             \
    int abi = 0;                                                                      \
    _Pragma("unroll 1")                                                               \
    for (int t = 0; t < T; ++t) {                                                     \
        const int aB = abi * 16384;                                                   \
        const int bB = 49152 + (t & 1) * 16384;                                       \
        const int aN = (abi >= 1 ? abi - 1 : 2) * 16384;                              \
        const int bN = 49152 + ((t + 1) & 1) * 16384;                                 \
        bf16x8 a[4][4], b[4][2];                                                      \
        /* ALL 24 operand reads first (kk-major) */                                   \
        _Pragma("unroll")                                                             \
        for (int mi = 0; mi < 4; ++mi) {                                              \
            a[0][mi] = *(const bf16x8*)(lds + aB + arow + mi * 2048 + s0);            \
            a[1][mi] = *(const bf16x8*)(lds + aB + arow + mi * 2048 + s1);            \
            a[2][mi] = *(const bf16x8*)(lds + aB + arow + mi * 2048 + s2);            \
            a[3][mi] = *(const bf16x8*)(lds + aB + arow + mi * 2048 + s3);            \
        }                                                                             \
        _Pragma("unroll")                                                             \
        for (int ni = 0; ni < 2; ++ni) {                                              \
            b[0][ni] = *(const bf16x8*)(lds + bB + brow2 + ni * 2048 + s0);           \
            b[1][ni] = *(const bf16x8*)(lds + bB + brow2 + ni * 2048 + s1);           \
            b[2][ni] = *(const bf16x8*)(lds + bB + brow2 + ni * 2048 + s2);           \
            b[3][ni] = *(const bf16x8*)(lds + bB + brow2 + ni * 2048 + s3);           \
        }                                                                             \
        /* stages after reads: deadline is tile-end vmcnt, huge slack */              \
        if (t + 1 < T) {                                                              \
            STAGE(Bt, bcol, t + 1, 0, bN); STAGE(Bt, bcol, t + 1, 1, bN);             \
            STAGE(Bt, bcol, t + 1, 2, bN); STAGE(Bt, bcol, t + 1, 3, bN);             \
        }                                                                             \
        if (t + 2 < T) {                                                              \
            STAGE(A, brow, t + 2, 0, aN); STAGE(A, brow, t + 2, 1, aN);               \
            STAGE(A, brow, t + 2, 2, aN); STAGE(A, brow, t + 2, 3, aN);               \
        }                                                                             \
        /* 32 MFMA (32x32x16), kk-major so acc chains are 4-long w/ 8-way ILP */      \
        _Pragma("unroll")                                                             \
        for (int kk = 0; kk < 4; ++kk) {                                              \
            _Pragma("unroll")                                                         \
            for (int mi = 0; mi < 4; ++mi) {                                          \
                _Pragma("unroll")                                                     \
                for (int ni = 0; ni < 2; ++ni)                                        \
                    acc[mi][ni] = __builtin_amdgcn_mfma_f32_32x32x16_bf16(            \
                        a[kk][mi], b[kk][ni], acc[mi][ni], 0, 0, 0);                  \
            }                                                                         \
        }                                                                             \
        if (t < T - 2) { asm volatile("s_waitcnt vmcnt(4)" ::: "memory"); }           \
        else           { asm volatile("s_waitcnt vmcnt(0)" ::: "memory"); }           \
        __builtin_amdgcn_s_barrier();                                                 \
        abi = (abi == 2) ? 0 : abi + 1;                                               \
    }

// ---------------- plain GEMM with split-K x2 (used for GEMM1) ----------
__global__ __launch_bounds__(512, 2)
void gemm256a_k(const u16* __restrict__ A, const u16* __restrict__ Bt,
                float* __restrict__ C, int M, int N, int Kd) {
    extern __shared__ u16 lds[];
    const int nwg = (M >> 8) * (N >> 8);
    int bid = blockIdx.x;
    const int half = (bid >= nwg) ? 1 : 0;
    if (half) bid -= nwg;
    const int KdH = Kd >> 1;
    const int koff = half * KdH;
    float* Cp = C + (size_t)half * ((size_t)M * N);
    GEMM_PRO_AND_KLOOP(KdH >> 6);
    #pragma unroll
    for (int mi = 0; mi < 4; ++mi) {
        #pragma unroll
        for (int ni = 0; ni < 2; ++ni) {
            const size_t cb = bcol + wn * 64 + ni * 32 + r5;
            #pragma unroll
            for (int reg = 0; reg < 16; ++reg) {
                const size_t rb = brow + wm * 128 + mi * 32
                                + (reg & 3) + 8 * (reg >> 2) + 4 * hk;
                Cp[rb * (size_t)N + cb] = acc[mi][ni][reg];
            }
        }
    }
}

// ---------------- GEMM + fused softmax partials (used for GEMM2) --------
__global__ __launch_bounds__(512, 2)
void gemm256s_k(const u16* __restrict__ A, const u16* __restrict__ Bt,
                float* __restrict__ C, int M, int N, int Kd,
                float2* __restrict__ pst) {
    extern __shared__ u16 lds[];
    const int nwg = (M >> 8) * (N >> 8);
    int bid = blockIdx.x;
    const int koff = 0;
    GEMM_PRO_AND_KLOOP(Kd >> 6);

    // epilogue: stats + C stores. For fixed (mi,reg) all 32 lanes of a
    // half hold the SAME row (cols = r5, +32 for ni=1) -> in-lane combine
    // over ni then 32-lane butterfly; lane r5==0 of each half writes.
    float2* sbuf = (float2*)lds;               // [256][5] float2, padded
    #pragma unroll
    for (int mi = 0; mi < 4; ++mi) {
        #pragma unroll
        for (int reg = 0; reg < 16; ++reg) {
            const float v0 = acc[mi][0][reg], v1 = acc[mi][1][reg];
            float mx = fmaxf(v0, v1);
            #pragma unroll
            for (int o = 1; o < 32; o <<= 1) mx = fmaxf(mx, __shfl_xor(mx, o));
            float se = __expf(v0 - mx) + __expf(v1 - mx);
            #pragma unroll
            for (int o = 1; o < 32; o <<= 1) se += __shfl_xor(se, o);
            if (r5 == 0) {
                const int rl = wm * 128 + mi * 32 + (reg & 3) + 8 * (reg >> 2) + 4 * hk;
                sbuf[rl * 5 + wn] = make_float2(mx, se);
            }
        }
        #pragma unroll
        for (int ni = 0; ni < 2; ++ni) {
            const size_t cb = bcol + wn * 64 + ni * 32 + r5;
            #pragma unroll
            for (int reg = 0; reg < 16; ++reg) {
                const size_t rb = brow + wm * 128 + mi * 32
                                + (reg & 3) + 8 * (reg >> 2) + 4 * hk;
                C[rb * (size_t)N + cb] = acc[mi][ni][reg];
            }
        }
    }
    // combine 4 wn partials per row; wait LDS only (NOT the C stores).
    asm volatile("s_waitcnt lgkmcnt(0)" ::: "memory");
    __builtin_amdgcn_s_barrier();
    if (tid < 256) {
        const float2 p0 = sbuf[tid * 5 + 0], p1 = sbuf[tid * 5 + 1];
        const float2 p2 = sbuf[tid * 5 + 2], p3 = sbuf[tid * 5 + 3];
        const float M2 = fmaxf(fmaxf(p0.x, p1.x), fmaxf(p2.x, p3.x));
        const float S2 = p0.y * __expf(p0.x - M2) + p1.y * __expf(p1.x - M2)
                       + p2.y * __expf(p2.x - M2) + p3.y * __expf(p3.x - M2);
        pst[(brow + tid) * (N >> 8) + bn] = make_float2(M2, S2);
    }
}

// ---------------- final per-row loss from partials + diagonal ----------
__global__ __launch_bounds__(256)
void loss_final_k(const float2* __restrict__ pst, const float* __restrict__ logits,
                  float* __restrict__ peld, float* __restrict__ pelp) {
    const int tid = threadIdx.x;
    const int wv = tid >> 6, half = (tid & 63) >> 5, l5 = tid & 31;
    const int row = blockIdx.x * 8 + wv * 2 + half;
    const float2 p = pst[(size_t)row * 32 + l5];
    const float d = logits[(size_t)row * (KSEL + 1)];   // diagonal
    float M = p.x;
    #pragma unroll
    for (int o = 1; o < 32; o <<= 1) M = fmaxf(M, __shfl_xor(M, o));
    float S = p.y * __expf(p.x - M);
    #pragma unroll
    for (int o = 1; o < 32; o <<= 1) S += __shfl_xor(S, o);
    if (l5 == 0) {
        const float pi = __expf(d - M) / S;
        peld[row] = 2.0f - 2.0f * pi + (float)(KSEL - 2) * PD_EPS;
        pelp[row] = M + __logf(S) - d;
    }
}

// ---------------- block reduce helpers ----------------
__device__ inline float blockSum(float v, float* red) {
    #pragma unroll
    for (int o = 32; o > 0; o >>= 1) v += __shfl_down(v, o);
    __syncthreads();
    if ((threadIdx.x & 63) == 0) red[threadIdx.x >> 6] = v;
    __syncthreads();
    return red[0] + red[1] + red[2] + red[3];
}

// ---------------- bias + LayerNorm (sum of 2 split-K planes) -> bf16 ----
__global__ void ln_k(const float* __restrict__ Hp0, const float* __restrict__ Hp1,
                     const float* __restrict__ bias,
                     const float* __restrict__ gamma, const float* __restrict__ beta,
                     u16* __restrict__ Hb) {
    __shared__ float red[4];
    const int r = blockIdx.x, t = threadIdx.x;
    float4 x4 = *(const float4*)(Hp0 + (size_t)r * HD + t * 4);
    float4 y4 = *(const float4*)(Hp1 + (size_t)r * HD + t * 4);
    float4 b4 = *(const float4*)(bias + t * 4);
    float x[4] = { x4.x + y4.x + b4.x, x4.y + y4.y + b4.y,
                   x4.z + y4.z + b4.z, x4.w + y4.w + b4.w };
    float s = x[0] + x[1] + x[2] + x[3];
    float mu = blockSum(s, red) * (1.0f / HD);
    float d0 = x[0] - mu, d1 = x[1] - mu, d2 = x[2] - mu, d3 = x[3] - mu;
    float vs = d0 * d0 + d1 * d1 + d2 * d2 + d3 * d3;
    float var = blockSum(vs, red) * (1.0f / HD);
    float rs = rsqrtf(var + LN_EPS);
    float4 g4 = *(const float4*)(gamma + t * 4);
    float4 e4 = *(const float4*)(beta + t * 4);
    float y0 = d0 * rs * g4.x + e4.x;
    float y1 = d1 * rs * g4.y + e4.y;
    float y2 = d2 * rs * g4.z + e4.z;
    float y3 = d3 * rs * g4.w + e4.w;
    *(uint2*)(Hb + (size_t)r * HD + t * 4) = pack4(y0, y1, y2, y3);
}

// ---------------- deterministic two-stage f64 reduction ----------------
__global__ __launch_bounds__(1024)
void reduce_k(const float* __restrict__ peld, const float* __restrict__ pelp,
              float* __restrict__ scalars) {
    __shared__ double red[4][16];
    const int t = threadIdx.x;
    double a = 0.0, b = 0.0, c = 0.0, d = 0.0;
    for (int i = t; i < KSEL; i += 1024) {
        const double pd = (double)peld[i];
        const double pp = (double)pelp[i];
        a += pd; b += pd * pd; c += pp; d += pp * pp;
    }
    #pragma unroll
    for (int o = 32; o > 0; o >>= 1) {
        a += __shfl_down(a, o); b += __shfl_down(b, o);
        c += __shfl_down(c, o); d += __shfl_down(d, o);
    }
    const int wv = t >> 6;
    if ((t & 63) == 0) { red[0][wv] = a; red[1][wv] = b; red[2][wv] = c; red[3][wv] = d; }
    __syncthreads();
    if (t == 0) {
        double s1 = 0, s2 = 0, s3 = 0, s4 = 0;
        #pragma unroll
        for (int i = 0; i < 16; ++i) { s1 += red[0][i]; s2 += red[1][i]; s3 += red[2][i]; s4 += red[3][i]; }
        const double Kd = (double)KSEL;
        const double denom = Kd + 1e-5;
        scalars[0] = (float)(s1 / denom);
        scalars[1] = (float)(s3 / denom);
        scalars[2] = (float)((s2 - s1 * s1 / Kd) / (Kd - 1.0));
        scalars[3] = (float)((s4 - s3 * s3 / Kd) / (Kd - 1.0));
    }
}

extern "C" void kernel_launch(void* const* d_in, const int* in_sizes, int n_in,
                              void* d_out, int out_size, void* d_ws, size_t ws_size,
                              hipStream_t stream) {
    const float* msp   = (const float*)d_in[0];
    const float* lab   = (const float*)d_in[1];
    const void*  mask  = d_in[2];
    const float* W     = (const float*)d_in[3];
    const float* bias  = (const float*)d_in[4];
    const float* gamma = (const float*)d_in[5];
    const float* beta  = (const float*)d_in[6];
    float* out = (float*)d_out;
    char*  ws  = (char*)d_ws;

    int*    idx     = (int*)ws;                         // 32 KB
    float2* pst     = (float2*)(ws + 65536);            // 2 MB, reuses wBf region after GEMM1
    u16*    wBf     = (u16*)(ws + 65536);               // 2 MB
    u16*    labelsB = (u16*)(ws + (size_t)(4  << 20));  // 16 MB
    u16*    hB      = (u16*)(ws + (size_t)(20 << 20));  // 16 MB
    u16*    predsB  = (u16*)d_out;                      // 16 MB scratch (dead before GEMM2)
    float*  hPre    = out + ((size_t)8 << 20);          // 2 planes x 32 MB (dead before GEMM2)

    float* peld    = out + (size_t)KSEL * KSEL;
    float* pelp    = peld + KSEL;
    float* scalars = pelp + KSEL;

    hipFuncSetAttribute(reinterpret_cast<const void*>(&gemm256a_k),
                        hipFuncAttributeMaxDynamicSharedMemorySize, 163840);
    hipFuncSetAttribute(reinterpret_cast<const void*>(&gemm256s_k),
                        hipFuncAttributeMaxDynamicSharedMemorySize, 163840);

    compact_mask_k<<<1, 1024, 0, stream>>>((const uint8_t*)mask, (const int32_t*)mask, idx);
    gather_conv_k<<<KSEL + 1024, 256, 0, stream>>>(msp, lab, idx, W, predsB, labelsB, wBf);
    gemm256a_k<<<2 * (KSEL / 256) * (HD / 256), 512, 163840, stream>>>(
        predsB, wBf, hPre, KSEL, HD, HD);
    ln_k<<<KSEL, 256, 0, stream>>>(hPre, hPre + (size_t)KSEL * HD, bias, gamma, beta, hB);
    gemm256s_k<<<(KSEL / 256) * (KSEL / 256), 512, 163840, stream>>>(
        hB, labelsB, out, KSEL, KSEL, HD, pst);
    loss_final_k<<<KSEL / 8, 256, 0, stream>>>(pst, out, peld, pelp);
    reduce_k<<<1, 1024, 0, stream>>>(peld, pelp, scalars);
}

// Round 14
// 255.492 us; speedup vs baseline: 1.3131x; 1.3131x over previous
//
#include <hip/hip_runtime.h>
#include <cstdint>

#define NROWS 32768
#define HD    1024
#define KSEL  8192
#define LN_EPS 1e-12f
#define PD_EPS 1e-6f

typedef unsigned short u16;
typedef __bf16 bf16x8 __attribute__((ext_vector_type(8)));
typedef float  f32x4  __attribute__((ext_vector_type(4)));

__device__ inline u16 f2bf(float f) {
    union { float f; uint32_t u; } x; x.f = f;
    uint32_t r = (x.u + 0x7fffu + ((x.u >> 16) & 1u)) >> 16;
    return (u16)r;
}

__device__ inline uint2 pack4(float a, float b, float c, float d) {
    uint2 r;
    r.x = (uint32_t)f2bf(a) | ((uint32_t)f2bf(b) << 16);
    r.y = (uint32_t)f2bf(c) | ((uint32_t)f2bf(d) << 16);
    return r;
}

// ---------------- fp8 e4m3 packing ----------------
__device__ inline uint32_t enc_e4m3(float f) {
    union { float f; uint32_t u; } x; x.f = f;
    uint32_t s = (x.u >> 31) << 7;
    float a = fabsf(f);
    if (a >= 448.f) return s | 0x7e;
    if (a < 0.001953125f) {
        int q = (int)(a * 512.f + 0.5f);
        return s | (uint32_t)q;
    }
    int e; float m = frexpf(a, &e);
    int E = e - 1 + 7;
    int q = (int)((m * 2.f - 1.f) * 8.f + 0.5f);
    if (q == 8) { q = 0; E += 1; }
    if (E >= 16) return s | 0x7e;
    if (E <= 0) { int qq = (int)(a * 512.f + 0.5f); return s | (uint32_t)qq; }
    return s | (uint32_t)(E << 3) | (uint32_t)q;
}

__device__ inline uint32_t pack4_f8(float a, float b, float c, float d) {
#if defined(__has_builtin) && __has_builtin(__builtin_amdgcn_cvt_pk_fp8_f32)
    int v = __builtin_amdgcn_cvt_pk_fp8_f32(a, b, 0, false);
    v = __builtin_amdgcn_cvt_pk_fp8_f32(c, d, v, true);
    return (uint32_t)v;
#else
    return enc_e4m3(a) | (enc_e4m3(b) << 8) | (enc_e4m3(c) << 16) | (enc_e4m3(d) << 24);
#endif
}

// ---------------- mask compaction (layout-robust) ----------------
__global__ void compact_mask_k(const uint8_t* mb, const int32_t* mi, int* idx) {
    __shared__ int cnt[1024];
    __shared__ int tmp[1024];
    __shared__ int mode_s;
    const int t = threadIdx.x;
    const int per = NROWS / 1024;      // 32
    const int base = t * per;
    int c0 = 0;
    for (int i = 0; i < per; ++i) c0 += (mb[base + i] != 0);
    tmp[t] = c0;
    __syncthreads();
    for (int off = 512; off > 0; off >>= 1) {
        if (t < off) tmp[t] += tmp[t + off];
        __syncthreads();
    }
    if (t == 0) mode_s = (tmp[0] == KSEL) ? 0 : 1;
    __syncthreads();
    const int mode = mode_s;
    int c = c0;
    if (mode) { c = 0; for (int i = 0; i < per; ++i) c += (mi[base + i] != 0); }
    cnt[t] = c;
    __syncthreads();
    for (int off = 1; off < 1024; off <<= 1) {
        int add = (t >= off) ? cnt[t - off] : 0;
        __syncthreads();
        cnt[t] += add;
        __syncthreads();
    }
    int pos = cnt[t] - c;
    for (int i = 0; i < per; ++i) {
        bool v = mode ? (mi[base + i] != 0) : (mb[base + i] != 0);
        if (v) idx[pos++] = base + i;
    }
}

// -- gather selected rows -> bf16(preds) + fp8(labels), fused with W->bf16 --
__global__ void gather_conv_k(const float* __restrict__ msp, const float* __restrict__ lab,
                              const int* __restrict__ idx, const float* __restrict__ W,
                              u16* __restrict__ predsB, uint8_t* __restrict__ labelsB8,
                              u16* __restrict__ Wb) {
    const int b = blockIdx.x;
    const int t = threadIdx.x;
    if (b < KSEL) {
        const int src = idx[b];
        float4 p = *(const float4*)(msp + (size_t)src * HD + t * 4);
        float4 q = *(const float4*)(lab + (size_t)src * HD + t * 4);
        *(uint2*)(predsB + (size_t)b * HD + t * 4) = pack4(p.x, p.y, p.z, p.w);
        *(uint32_t*)(labelsB8 + (size_t)b * HD + t * 4) = pack4_f8(q.x, q.y, q.z, q.w);
    } else {
        const int i = ((b - KSEL) * 256 + t) * 4;   // 1024 blocks cover HD*HD
        float4 v = *(const float4*)(W + i);
        *(uint2*)(Wb + i) = pack4(v.x, v.y, v.z, v.w);
    }
}

// =======================================================================
// bf16 GEMM (GEMM1): r11 structure verbatim — 256x256 tile, BK=64,
// 8 waves, acc[8][4] 16x16x32, full-tile operand prefetch, one counted
// vmcnt(4)+barrier per tile, slot^(row&7) swizzle (both-sides).
// =======================================================================
#define STAGE(XPTR, ROWBASE, KT, I, LBASE) do {                                      \
    const int f_ = (I) * 512 + tid;                                                  \
    const int r_ = f_ >> 3;                                                          \
    const int sp_ = (f_ & 7) ^ (r_ & 7);                                             \
    const u16* g_ = (XPTR) + (size_t)((ROWBASE) + r_) * Kd + koff + (KT) * 64 + sp_ * 8; \
    __builtin_amdgcn_global_load_lds(                                                \
        (const __attribute__((address_space(1))) void*)g_,                           \
        (__attribute__((address_space(3))) void*)(lds + (LBASE) + f_ * 8), 16, 0, 0);\
} while (0)

__global__ __launch_bounds__(512, 2)
void gemm256a_k(const u16* __restrict__ A, const u16* __restrict__ Bt,
                float* __restrict__ C, int M, int N, int Kd) {
    extern __shared__ u16 lds[];
    const int nwg = (M >> 8) * (N >> 8);
    int bid = blockIdx.x;
    const int half = (bid >= nwg) ? 1 : 0;
    if (half) bid -= nwg;
    const int KdH = Kd >> 1;
    const int koff = half * KdH;
    float* Cp = C + (size_t)half * ((size_t)M * N);

    const int nx  = N >> 8;
    int wg  = ((nwg & 7) == 0) ? ((bid & 7) * (nwg >> 3) + (bid >> 3)) : bid;
    const int bm = wg / nx, bn = wg % nx;
    const size_t brow = (size_t)bm << 8, bcol = (size_t)bn << 8;
    const int tid = threadIdx.x;
    const int l = tid & 63, wid = tid >> 6;
    const int wm = wid >> 2, wn = wid & 3;
    const int lr = l & 15, lq = l >> 4;
    const int sw = lr & 7;
    f32x4 acc[8][4] = {};
    const int arow = (wm * 128 + lr) * 64;
    const int brow2 = (wn * 64 + lr) * 64;
    const int s0 = (lq ^ sw) * 8;
    const int s1 = ((4 + lq) ^ sw) * 8;
    #pragma unroll
    for (int i = 0; i < 4; ++i) STAGE(A,  brow, 0, i, 0);
    #pragma unroll
    for (int i = 0; i < 4; ++i) STAGE(Bt, bcol, 0, i, 49152);
    #pragma unroll
    for (int i = 0; i < 4; ++i) STAGE(A,  brow, 1, i, 16384);
    asm volatile("s_waitcnt vmcnt(4)" ::: "memory");
    __builtin_amdgcn_s_barrier();
    const int T = KdH >> 6;
    int abi = 0;
    #pragma unroll 1
    for (int t = 0; t < T; ++t) {
        const int aB = abi * 16384;
        const int bB = 49152 + (t & 1) * 16384;
        const int aN = (abi >= 1 ? abi - 1 : 2) * 16384;
        const int bN = 49152 + ((t + 1) & 1) * 16384;
        bf16x8 a0[8], b0[4], a1[8], b1[4];
        #pragma unroll
        for (int mi = 0; mi < 8; ++mi)
            a0[mi] = *(const bf16x8*)(lds + aB + arow + mi * 1024 + s0);
        #pragma unroll
        for (int ni = 0; ni < 4; ++ni)
            b0[ni] = *(const bf16x8*)(lds + bB + brow2 + ni * 1024 + s0);
        #pragma unroll
        for (int mi = 0; mi < 8; ++mi)
            a1[mi] = *(const bf16x8*)(lds + aB + arow + mi * 1024 + s1);
        #pragma unroll
        for (int ni = 0; ni < 4; ++ni)
            b1[ni] = *(const bf16x8*)(lds + bB + brow2 + ni * 1024 + s1);
        if (t + 1 < T) {
            STAGE(Bt, bcol, t + 1, 0, bN); STAGE(Bt, bcol, t + 1, 1, bN);
            STAGE(Bt, bcol, t + 1, 2, bN); STAGE(Bt, bcol, t + 1, 3, bN);
        }
        if (t + 2 < T) {
            STAGE(A, brow, t + 2, 0, aN); STAGE(A, brow, t + 2, 1, aN);
            STAGE(A, brow, t + 2, 2, aN); STAGE(A, brow, t + 2, 3, aN);
        }
        #pragma unroll
        for (int mi = 0; mi < 8; ++mi) {
            #pragma unroll
            for (int ni = 0; ni < 4; ++ni)
                acc[mi][ni] = __builtin_amdgcn_mfma_f32_16x16x32_bf16(a0[mi], b0[ni], acc[mi][ni], 0, 0, 0);
        }
        #pragma unroll
        for (int mi = 0; mi < 8; ++mi) {
            #pragma unroll
            for (int ni = 0; ni < 4; ++ni)
                acc[mi][ni] = __builtin_amdgcn_mfma_f32_16x16x32_bf16(a1[mi], b1[ni], acc[mi][ni], 0, 0, 0);
        }
        if (t < T - 2) { asm volatile("s_waitcnt vmcnt(4)" ::: "memory"); }
        else           { asm volatile("s_waitcnt vmcnt(0)" ::: "memory"); }
        __builtin_amdgcn_s_barrier();
        abi = (abi == 2) ? 0 : abi + 1;
    }
    #pragma unroll
    for (int m = 0; m < 8; ++m) {
        const size_t rb = brow + wm * 128 + m * 16 + lq * 4;
        #pragma unroll
        for (int n = 0; n < 4; ++n) {
            const size_t cb = bcol + wn * 64 + n * 16 + lr;
            #pragma unroll
            for (int rr = 0; rr < 4; ++rr)
                Cp[(rb + rr) * (size_t)N + cb] = acc[m][n][rr];
        }
    }
}

// =======================================================================
// fp8 GEMM (GEMM2): 256x256 tile, BK=128 (128B rows -> same proven bank
// geometry as bf16), 8 waves, 16x16x32 fp8_fp8 MFMA (same rate as bf16,
// HALF the staging + LDS-read bytes). Fragments: lane l -> row l&15,
// k=(l>>4)*8 (8 fp8 = b64); frag byte = ((kk*2+(lq>>1))^(lr&7))*16 +
// (lq&1)*8; 16B-slot swizzle slot^(row&7) identical to bf16 (verified
// 2-way residual per 32-lane service group). C/D layout dtype-independent
// -> epilogue identical to r11. Stages first (tile-end deadline), one
// counted vmcnt(4)+barrier per tile. LDS: A triple 3x32KB @0/32768/65536,
// B double @98304/131072 = 160KB.
// =======================================================================
#define STAGE8(XPTR, ROWBASE, KT, I, LBASE) do {                                     \
    const int f_ = (I) * 512 + tid;                                                  \
    const int r_ = f_ >> 3;                                                          \
    const int sp_ = (f_ & 7) ^ (r_ & 7);                                             \
    const uint8_t* g_ = (XPTR) + (size_t)((ROWBASE) + r_) * Kd + (KT) * 128 + sp_ * 16; \
    __builtin_amdgcn_global_load_lds(                                                \
        (const __attribute__((address_space(1))) void*)g_,                           \
        (__attribute__((address_space(3))) void*)(lds8 + (LBASE) + f_ * 16), 16, 0, 0);\
} while (0)

__global__ __launch_bounds__(512, 2)
void gemm256s_k(const uint8_t* __restrict__ A, const uint8_t* __restrict__ Bt,
                float* __restrict__ C, int M, int N, int Kd,
                float2* __restrict__ pst) {
    extern __shared__ u16 lds[];
    uint8_t* lds8 = (uint8_t*)lds;
    const int nx  = N >> 8;
    const int nwg = (M >> 8) * nx;
    int bid = blockIdx.x;
    int wg  = ((nwg & 7) == 0) ? ((bid & 7) * (nwg >> 3) + (bid >> 3)) : bid;
    const int bm = wg / nx, bn = wg % nx;
    const size_t brow = (size_t)bm << 8, bcol = (size_t)bn << 8;
    const int tid = threadIdx.x;
    const int l = tid & 63, wid = tid >> 6;
    const int wm = wid >> 2, wn = wid & 3;
    const int lr = l & 15, lq = l >> 4;
    const int sw = lr & 7;
    f32x4 acc[8][4] = {};
    const int arow = (wm * 128 + lr) * 128;     // byte offsets, 128B rows
    const int brow2 = (wn * 64 + lr) * 128;
    int fo[4];
    #pragma unroll
    for (int kk = 0; kk < 4; ++kk)
        fo[kk] = (((kk * 2 + (lq >> 1)) ^ sw) * 16) + (lq & 1) * 8;

    #pragma unroll
    for (int i = 0; i < 4; ++i) STAGE8(A,  brow, 0, i, 0);
    #pragma unroll
    for (int i = 0; i < 4; ++i) STAGE8(Bt, bcol, 0, i, 98304);
    #pragma unroll
    for (int i = 0; i < 4; ++i) STAGE8(A,  brow, 1, i, 32768);
    asm volatile("s_waitcnt vmcnt(4)" ::: "memory");
    __builtin_amdgcn_s_barrier();

    const int T = Kd >> 7;      // K-tiles of 128
    int abi = 0;
    #pragma unroll 1
    for (int t = 0; t < T; ++t) {
        const int aB = abi * 32768;
        const int bB = 98304 + (t & 1) * 32768;
        const int aN = (abi >= 1 ? abi - 1 : 2) * 32768;
        const int bN = 98304 + ((t + 1) & 1) * 32768;
        if (t + 1 < T) {
            STAGE8(Bt, bcol, t + 1, 0, bN); STAGE8(Bt, bcol, t + 1, 1, bN);
            STAGE8(Bt, bcol, t + 1, 2, bN); STAGE8(Bt, bcol, t + 1, 3, bN);
        }
        if (t + 2 < T) {
            STAGE8(A, brow, t + 2, 0, aN); STAGE8(A, brow, t + 2, 1, aN);
            STAGE8(A, brow, t + 2, 2, aN); STAGE8(A, brow, t + 2, 3, aN);
        }
        #pragma unroll
        for (int kk = 0; kk < 4; ++kk) {
            long a[8], b[4];
            #pragma unroll
            for (int mi = 0; mi < 8; ++mi)
                a[mi] = *(const long*)(lds8 + aB + arow + mi * 2048 + fo[kk]);
            #pragma unroll
            for (int ni = 0; ni < 4; ++ni)
                b[ni] = *(const long*)(lds8 + bB + brow2 + ni * 2048 + fo[kk]);
            #pragma unroll
            for (int mi = 0; mi < 8; ++mi) {
                #pragma unroll
                for (int ni = 0; ni < 4; ++ni)
                    acc[mi][ni] = __builtin_amdgcn_mfma_f32_16x16x32_fp8_fp8(
                        a[mi], b[ni], acc[mi][ni], 0, 0, 0);
            }
        }
        if (t < T - 2) { asm volatile("s_waitcnt vmcnt(4)" ::: "memory"); }
        else           { asm volatile("s_waitcnt vmcnt(0)" ::: "memory"); }
        __builtin_amdgcn_s_barrier();
        abi = (abi == 2) ? 0 : abi + 1;
    }

    // epilogue: per-m stats (native __expf) interleaved with C stores.
    float2* sbuf = (float2*)lds8;              // [256][5] float2, padded
    #pragma unroll
    for (int m = 0; m < 8; ++m) {
        #pragma unroll
        for (int rr = 0; rr < 4; ++rr) {
            float v0 = acc[m][0][rr], v1 = acc[m][1][rr];
            float v2 = acc[m][2][rr], v3 = acc[m][3][rr];
            float mx = fmaxf(fmaxf(v0, v1), fmaxf(v2, v3));
            #pragma unroll
            for (int o = 1; o < 16; o <<= 1) mx = fmaxf(mx, __shfl_xor(mx, o));
            float se = __expf(v0 - mx) + __expf(v1 - mx) + __expf(v2 - mx) + __expf(v3 - mx);
            #pragma unroll
            for (int o = 1; o < 16; o <<= 1) se += __shfl_xor(se, o);
            if (lr == 0) {
                const int rl = wm * 128 + m * 16 + lq * 4 + rr;
                sbuf[rl * 5 + wn] = make_float2(mx, se);
            }
        }
        const size_t rb = brow + wm * 128 + m * 16 + lq * 4;
        #pragma unroll
        for (int n = 0; n < 4; ++n) {
            const size_t cb = bcol + wn * 64 + n * 16 + lr;
            #pragma unroll
            for (int rr = 0; rr < 4; ++rr)
                C[(rb + rr) * (size_t)N + cb] = acc[m][n][rr];
        }
    }
    asm volatile("s_waitcnt lgkmcnt(0)" ::: "memory");
    __builtin_amdgcn_s_barrier();
    if (tid < 256) {
        const float2 p0 = sbuf[tid * 5 + 0], p1 = sbuf[tid * 5 + 1];
        const float2 p2 = sbuf[tid * 5 + 2], p3 = sbuf[tid * 5 + 3];
        const float M2 = fmaxf(fmaxf(p0.x, p1.x), fmaxf(p2.x, p3.x));
        const float S2 = p0.y * __expf(p0.x - M2) + p1.y * __expf(p1.x - M2)
                       + p2.y * __expf(p2.x - M2) + p3.y * __expf(p3.x - M2);
        pst[(brow + tid) * (N >> 8) + bn] = make_float2(M2, S2);
    }
}

// ---------------- final per-row loss from partials + diagonal ----------
__global__ __launch_bounds__(256)
void loss_final_k(const float2* __restrict__ pst, const float* __restrict__ logits,
                  float* __restrict__ peld, float* __restrict__ pelp) {
    const int tid = threadIdx.x;
    const int wv = tid >> 6, half = (tid & 63) >> 5, l5 = tid & 31;
    const int row = blockIdx.x * 8 + wv * 2 + half;
    const float2 p = pst[(size_t)row * 32 + l5];
    const float d = logits[(size_t)row * (KSEL + 1)];   // diagonal
    float M = p.x;
    #pragma unroll
    for (int o = 1; o < 32; o <<= 1) M = fmaxf(M, __shfl_xor(M, o));
    float S = p.y * __expf(p.x - M);
    #pragma unroll
    for (int o = 1; o < 32; o <<= 1) S += __shfl_xor(S, o);
    if (l5 == 0) {
        const float pi = __expf(d - M) / S;
        peld[row] = 2.0f - 2.0f * pi + (float)(KSEL - 2) * PD_EPS;
        pelp[row] = M + __logf(S) - d;
    }
}

// ---------------- block reduce helpers ----------------
__device__ inline float blockSum(float v, float* red) {
    #pragma unroll
    for (int o = 32; o > 0; o >>= 1) v += __shfl_down(v, o);
    __syncthreads();
    if ((threadIdx.x & 63) == 0) red[threadIdx.x >> 6] = v;
    __syncthreads();
    return red[0] + red[1] + red[2] + red[3];
}

// ------- bias + LayerNorm (sum of 2 split-K planes) -> fp8 ----------
__global__ void ln_k(const float* __restrict__ Hp0, const float* __restrict__ Hp1,
                     const float* __restrict__ bias,
                     const float* __restrict__ gamma, const float* __restrict__ beta,
                     uint8_t* __restrict__ Hb8) {
    __shared__ float red[4];
    const int r = blockIdx.x, t = threadIdx.x;
    float4 x4 = *(const float4*)(Hp0 + (size_t)r * HD + t * 4);
    float4 y4 = *(const float4*)(Hp1 + (size_t)r * HD + t * 4);
    float4 b4 = *(const float4*)(bias + t * 4);
    float x[4] = { x4.x + y4.x + b4.x, x4.y + y4.y + b4.y,
                   x4.z + y4.z + b4.z, x4.w + y4.w + b4.w };
    float s = x[0] + x[1] + x[2] + x[3];
    float mu = blockSum(s, red) * (1.0f / HD);
    float d0 = x[0] - mu, d1 = x[1] - mu, d2 = x[2] - mu, d3 = x[3] - mu;
    float vs = d0 * d0 + d1 * d1 + d2 * d2 + d3 * d3;
    float var = blockSum(vs, red) * (1.0f / HD);
    float rs = rsqrtf(var + LN_EPS);
    float4 g4 = *(const float4*)(gamma + t * 4);
    float4 e4 = *(const float4*)(beta + t * 4);
    float y0 = d0 * rs * g4.x + e4.x;
    float y1 = d1 * rs * g4.y + e4.y;
    float y2 = d2 * rs * g4.z + e4.z;
    float y3 = d3 * rs * g4.w + e4.w;
    *(uint32_t*)(Hb8 + (size_t)r * HD + t * 4) = pack4_f8(y0, y1, y2, y3);
}

// ---------------- deterministic two-stage f64 reduction ----------------
__global__ __launch_bounds__(1024)
void reduce_k(const float* __restrict__ peld, const float* __restrict__ pelp,
              float* __restrict__ scalars) {
    __shared__ double red[4][16];
    const int t = threadIdx.x;
    double a = 0.0, b = 0.0, c = 0.0, d = 0.0;
    for (int i = t; i < KSEL; i += 1024) {
        const double pd = (double)peld[i];
        const double pp = (double)pelp[i];
        a += pd; b += pd * pd; c += pp; d += pp * pp;
    }
    #pragma unroll
    for (int o = 32; o > 0; o >>= 1) {
        a += __shfl_down(a, o); b += __shfl_down(b, o);
        c += __shfl_down(c, o); d += __shfl_down(d, o);
    }
    const int wv = t >> 6;
    if ((t & 63) == 0) { red[0][wv] = a; red[1][wv] = b; red[2][wv] = c; red[3][wv] = d; }
    __syncthreads();
    if (t == 0) {
        double s1 = 0, s2 = 0, s3 = 0, s4 = 0;
        #pragma unroll
        for (int i = 0; i < 16; ++i) { s1 += red[0][i]; s2 += red[1][i]; s3 += red[2][i]; s4 += red[3][i]; }
        const double Kd = (double)KSEL;
        const double denom = Kd + 1e-5;
        scalars[0] = (float)(s1 / denom);
        scalars[1] = (float)(s3 / denom);
        scalars[2] = (float)((s2 - s1 * s1 / Kd) / (Kd - 1.0));
        scalars[3] = (float)((s4 - s3 * s3 / Kd) / (Kd - 1.0));
    }
}

extern "C" void kernel_launch(void* const* d_in, const int* in_sizes, int n_in,
                              void* d_out, int out_size, void* d_ws, size_t ws_size,
                              hipStream_t stream) {
    const float* msp   = (const float*)d_in[0];
    const float* lab   = (const float*)d_in[1];
    const void*  mask  = d_in[2];
    const float* W     = (const float*)d_in[3];
    const float* bias  = (const float*)d_in[4];
    const float* gamma = (const float*)d_in[5];
    const float* beta  = (const float*)d_in[6];
    float* out = (float*)d_out;
    char*  ws  = (char*)d_ws;

    int*     idx      = (int*)ws;                         // 32 KB
    float2*  pst      = (float2*)(ws + 65536);            // 2 MB, reuses wBf after GEMM1
    u16*     wBf      = (u16*)(ws + 65536);               // 2 MB
    uint8_t* labelsB8 = (uint8_t*)(ws + (size_t)(4  << 20)); // 8 MB
    uint8_t* hB8      = (uint8_t*)(ws + (size_t)(20 << 20)); // 8 MB
    u16*     predsB   = (u16*)d_out;                      // 16 MB scratch (dead before GEMM2)
    float*   hPre     = out + ((size_t)8 << 20);          // 2 planes x 32 MB (dead before GEMM2)

    float* peld    = out + (size_t)KSEL * KSEL;
    float* pelp    = peld + KSEL;
    float* scalars = pelp + KSEL;

    hipFuncSetAttribute(reinterpret_cast<const void*>(&gemm256a_k),
                        hipFuncAttributeMaxDynamicSharedMemorySize, 163840);
    hipFuncSetAttribute(reinterpret_cast<const void*>(&gemm256s_k),
                        hipFuncAttributeMaxDynamicSharedMemorySize, 163840);

    compact_mask_k<<<1, 1024, 0, stream>>>((const uint8_t*)mask, (const int32_t*)mask, idx);
    gather_conv_k<<<KSEL + 1024, 256, 0, stream>>>(msp, lab, idx, W, predsB, labelsB8, wBf);
    gemm256a_k<<<2 * (KSEL / 256) * (HD / 256), 512, 163840, stream>>>(
        predsB, wBf, hPre, KSEL, HD, HD);
    ln_k<<<KSEL, 256, 0, stream>>>(hPre, hPre + (size_t)KSEL * HD, bias, gamma, beta, hB8);
    gemm256s_k<<<(KSEL / 256) * (KSEL / 256), 512, 163840, stream>>>(
        hB8, labelsB8, out, KSEL, KSEL, HD, pst);
    loss_final_k<<<KSEL / 8, 256, 0, stream>>>(pst, out, peld, pelp);
    reduce_k<<<1, 1024, 0, stream>>>(peld, pelp, scalars);
}

// Round 15
// 230.621 us; speedup vs baseline: 1.4547x; 1.1078x over previous
//
#include <hip/hip_runtime.h>
#include <cstdint>

#define NROWS 32768
#define HD    1024
#define KSEL  8192
#define LN_EPS 1e-12f
#define PD_EPS 1e-6f

typedef unsigned short u16;
typedef __bf16 bf16x8 __attribute__((ext_vector_type(8)));
typedef float  f32x4  __attribute__((ext_vector_type(4)));
typedef int    v8i    __attribute__((ext_vector_type(8)));
typedef int    v4i    __attribute__((ext_vector_type(4)));

__device__ inline u16 f2bf(float f) {
    union { float f; uint32_t u; } x; x.f = f;
    uint32_t r = (x.u + 0x7fffu + ((x.u >> 16) & 1u)) >> 16;
    return (u16)r;
}

__device__ inline uint2 pack4(float a, float b, float c, float d) {
    uint2 r;
    r.x = (uint32_t)f2bf(a) | ((uint32_t)f2bf(b) << 16);
    r.y = (uint32_t)f2bf(c) | ((uint32_t)f2bf(d) << 16);
    return r;
}

// ---------------- fp8 e4m3 packing ----------------
__device__ inline uint32_t enc_e4m3(float f) {
    union { float f; uint32_t u; } x; x.f = f;
    uint32_t s = (x.u >> 31) << 7;
    float a = fabsf(f);
    if (a >= 448.f) return s | 0x7e;
    if (a < 0.001953125f) {
        int q = (int)(a * 512.f + 0.5f);
        return s | (uint32_t)q;
    }
    int e; float m = frexpf(a, &e);
    int E = e - 1 + 7;
    int q = (int)((m * 2.f - 1.f) * 8.f + 0.5f);
    if (q == 8) { q = 0; E += 1; }
    if (E >= 16) return s | 0x7e;
    if (E <= 0) { int qq = (int)(a * 512.f + 0.5f); return s | (uint32_t)qq; }
    return s | (uint32_t)(E << 3) | (uint32_t)q;
}

__device__ inline uint32_t pack4_f8(float a, float b, float c, float d) {
#if defined(__has_builtin) && __has_builtin(__builtin_amdgcn_cvt_pk_fp8_f32)
    int v = __builtin_amdgcn_cvt_pk_fp8_f32(a, b, 0, false);
    v = __builtin_amdgcn_cvt_pk_fp8_f32(c, d, v, true);
    return (uint32_t)v;
#else
    return enc_e4m3(a) | (enc_e4m3(b) << 8) | (enc_e4m3(c) << 16) | (enc_e4m3(d) << 24);
#endif
}

// ---------------- mask compaction (layout-robust) ----------------
__global__ void compact_mask_k(const uint8_t* mb, const int32_t* mi, int* idx) {
    __shared__ int cnt[1024];
    __shared__ int tmp[1024];
    __shared__ int mode_s;
    const int t = threadIdx.x;
    const int per = NROWS / 1024;      // 32
    const int base = t * per;
    int c0 = 0;
    for (int i = 0; i < per; ++i) c0 += (mb[base + i] != 0);
    tmp[t] = c0;
    __syncthreads();
    for (int off = 512; off > 0; off >>= 1) {
        if (t < off) tmp[t] += tmp[t + off];
        __syncthreads();
    }
    if (t == 0) mode_s = (tmp[0] == KSEL) ? 0 : 1;
    __syncthreads();
    const int mode = mode_s;
    int c = c0;
    if (mode) { c = 0; for (int i = 0; i < per; ++i) c += (mi[base + i] != 0); }
    cnt[t] = c;
    __syncthreads();
    for (int off = 1; off < 1024; off <<= 1) {
        int add = (t >= off) ? cnt[t - off] : 0;
        __syncthreads();
        cnt[t] += add;
        __syncthreads();
    }
    int pos = cnt[t] - c;
    for (int i = 0; i < per; ++i) {
        bool v = mode ? (mi[base + i] != 0) : (mb[base + i] != 0);
        if (v) idx[pos++] = base + i;
    }
}

// -- gather selected rows -> bf16(preds) + fp8(labels), fused with W->bf16 --
__global__ void gather_conv_k(const float* __restrict__ msp, const float* __restrict__ lab,
                              const int* __restrict__ idx, const float* __restrict__ W,
                              u16* __restrict__ predsB, uint8_t* __restrict__ labelsB8,
                              u16* __restrict__ Wb) {
    const int b = blockIdx.x;
    const int t = threadIdx.x;
    if (b < KSEL) {
        const int src = idx[b];
        float4 p = *(const float4*)(msp + (size_t)src * HD + t * 4);
        float4 q = *(const float4*)(lab + (size_t)src * HD + t * 4);
        *(uint2*)(predsB + (size_t)b * HD + t * 4) = pack4(p.x, p.y, p.z, p.w);
        *(uint32_t*)(labelsB8 + (size_t)b * HD + t * 4) = pack4_f8(q.x, q.y, q.z, q.w);
    } else {
        const int i = ((b - KSEL) * 256 + t) * 4;   // 1024 blocks cover HD*HD
        float4 v = *(const float4*)(W + i);
        *(uint2*)(Wb + i) = pack4(v.x, v.y, v.z, v.w);
    }
}

// =======================================================================
// bf16 GEMM (GEMM1): r11 structure verbatim — 256x256 tile, BK=64,
// 8 waves, acc[8][4] 16x16x32, full-tile operand prefetch, one counted
// vmcnt(4)+barrier per tile, slot^(row&7) swizzle (both-sides).
// =======================================================================
#define STAGE(XPTR, ROWBASE, KT, I, LBASE) do {                                      \
    const int f_ = (I) * 512 + tid;                                                  \
    const int r_ = f_ >> 3;                                                          \
    const int sp_ = (f_ & 7) ^ (r_ & 7);                                             \
    const u16* g_ = (XPTR) + (size_t)((ROWBASE) + r_) * Kd + koff + (KT) * 64 + sp_ * 8; \
    __builtin_amdgcn_global_load_lds(                                                \
        (const __attribute__((address_space(1))) void*)g_,                           \
        (__attribute__((address_space(3))) void*)(lds + (LBASE) + f_ * 8), 16, 0, 0);\
} while (0)

__global__ __launch_bounds__(512, 2)
void gemm256a_k(const u16* __restrict__ A, const u16* __restrict__ Bt,
                float* __restrict__ C, int M, int N, int Kd) {
    extern __shared__ u16 lds[];
    const int nwg = (M >> 8) * (N >> 8);
    int bid = blockIdx.x;
    const int half = (bid >= nwg) ? 1 : 0;
    if (half) bid -= nwg;
    const int KdH = Kd >> 1;
    const int koff = half * KdH;
    float* Cp = C + (size_t)half * ((size_t)M * N);

    const int nx  = N >> 8;
    int wg  = ((nwg & 7) == 0) ? ((bid & 7) * (nwg >> 3) + (bid >> 3)) : bid;
    const int bm = wg / nx, bn = wg % nx;
    const size_t brow = (size_t)bm << 8, bcol = (size_t)bn << 8;
    const int tid = threadIdx.x;
    const int l = tid & 63, wid = tid >> 6;
    const int wm = wid >> 2, wn = wid & 3;
    const int lr = l & 15, lq = l >> 4;
    const int sw = lr & 7;
    f32x4 acc[8][4] = {};
    const int arow = (wm * 128 + lr) * 64;
    const int brow2 = (wn * 64 + lr) * 64;
    const int s0 = (lq ^ sw) * 8;
    const int s1 = ((4 + lq) ^ sw) * 8;
    #pragma unroll
    for (int i = 0; i < 4; ++i) STAGE(A,  brow, 0, i, 0);
    #pragma unroll
    for (int i = 0; i < 4; ++i) STAGE(Bt, bcol, 0, i, 49152);
    #pragma unroll
    for (int i = 0; i < 4; ++i) STAGE(A,  brow, 1, i, 16384);
    asm volatile("s_waitcnt vmcnt(4)" ::: "memory");
    __builtin_amdgcn_s_barrier();
    const int T = KdH >> 6;
    int abi = 0;
    #pragma unroll 1
    for (int t = 0; t < T; ++t) {
        const int aB = abi * 16384;
        const int bB = 49152 + (t & 1) * 16384;
        const int aN = (abi >= 1 ? abi - 1 : 2) * 16384;
        const int bN = 49152 + ((t + 1) & 1) * 16384;
        bf16x8 a0[8], b0[4], a1[8], b1[4];
        #pragma unroll
        for (int mi = 0; mi < 8; ++mi)
            a0[mi] = *(const bf16x8*)(lds + aB + arow + mi * 1024 + s0);
        #pragma unroll
        for (int ni = 0; ni < 4; ++ni)
            b0[ni] = *(const bf16x8*)(lds + bB + brow2 + ni * 1024 + s0);
        #pragma unroll
        for (int mi = 0; mi < 8; ++mi)
            a1[mi] = *(const bf16x8*)(lds + aB + arow + mi * 1024 + s1);
        #pragma unroll
        for (int ni = 0; ni < 4; ++ni)
            b1[ni] = *(const bf16x8*)(lds + bB + brow2 + ni * 1024 + s1);
        if (t + 1 < T) {
            STAGE(Bt, bcol, t + 1, 0, bN); STAGE(Bt, bcol, t + 1, 1, bN);
            STAGE(Bt, bcol, t + 1, 2, bN); STAGE(Bt, bcol, t + 1, 3, bN);
        }
        if (t + 2 < T) {
            STAGE(A, brow, t + 2, 0, aN); STAGE(A, brow, t + 2, 1, aN);
            STAGE(A, brow, t + 2, 2, aN); STAGE(A, brow, t + 2, 3, aN);
        }
        #pragma unroll
        for (int mi = 0; mi < 8; ++mi) {
            #pragma unroll
            for (int ni = 0; ni < 4; ++ni)
                acc[mi][ni] = __builtin_amdgcn_mfma_f32_16x16x32_bf16(a0[mi], b0[ni], acc[mi][ni], 0, 0, 0);
        }
        #pragma unroll
        for (int mi = 0; mi < 8; ++mi) {
            #pragma unroll
            for (int ni = 0; ni < 4; ++ni)
                acc[mi][ni] = __builtin_amdgcn_mfma_f32_16x16x32_bf16(a1[mi], b1[ni], acc[mi][ni], 0, 0, 0);
        }
        if (t < T - 2) { asm volatile("s_waitcnt vmcnt(4)" ::: "memory"); }
        else           { asm volatile("s_waitcnt vmcnt(0)" ::: "memory"); }
        __builtin_amdgcn_s_barrier();
        abi = (abi == 2) ? 0 : abi + 1;
    }
    #pragma unroll
    for (int m = 0; m < 8; ++m) {
        const size_t rb = brow + wm * 128 + m * 16 + lq * 4;
        #pragma unroll
        for (int n = 0; n < 4; ++n) {
            const size_t cb = bcol + wn * 64 + n * 16 + lr;
            #pragma unroll
            for (int rr = 0; rr < 4; ++rr)
                Cp[(rb + rr) * (size_t)N + cb] = acc[m][n][rr];
        }
    }
}

// =======================================================================
// MX-fp8 GEMM (GEMM2): 256x256 tile, BK=128 fp8-bytes, 8 waves,
// mfma_scale_f32_16x16x128_f8f6f4 with UNIT scales (e8m0 0x7F = exact
// 1.0 -> numerically identical to plain fp8, 2x MFMA rate).
// r14 lesson: b64 fragment reads are fundamentally 2-way bank-conflicted
// (16-lane service group, h=lq&1 group-uniform -> only 8 distinct 8B
// slots/128B period; 1.26e7 conflicts). 16x16x128 fragments are 32
// CONTIGUOUS bytes per lane (k=(l>>4)*32) -> two b128 reads with the
// r11-proven slot^(row&7) swizzle geometry = 0 conflicts.
// Staging/LDS/sync identical to r14: STAGE8 16B blocks, A triple 3x32KB
// @0/32768/65536, B double @98304/131072; one counted vmcnt(4)+barrier
// per K-tile (T=8 tiles of K=128).
// =======================================================================
#define STAGE8(XPTR, ROWBASE, KT, I, LBASE) do {                                     \
    const int f_ = (I) * 512 + tid;                                                  \
    const int r_ = f_ >> 3;                                                          \
    const int sp_ = (f_ & 7) ^ (r_ & 7);                                             \
    const uint8_t* g_ = (XPTR) + (size_t)((ROWBASE) + r_) * Kd + (KT) * 128 + sp_ * 16; \
    __builtin_amdgcn_global_load_lds(                                                \
        (const __attribute__((address_space(1))) void*)g_,                           \
        (__attribute__((address_space(3))) void*)(lds8 + (LBASE) + f_ * 16), 16, 0, 0);\
} while (0)

__device__ inline v8i ld_frag32(const uint8_t* p0, const uint8_t* p1) {
    v4i lo = *(const v4i*)p0;
    v4i hi = *(const v4i*)p1;
    v8i r;
    r[0] = lo[0]; r[1] = lo[1]; r[2] = lo[2]; r[3] = lo[3];
    r[4] = hi[0]; r[5] = hi[1]; r[6] = hi[2]; r[7] = hi[3];
    return r;
}

__global__ __launch_bounds__(512, 2)
void gemm256s_k(const uint8_t* __restrict__ A, const uint8_t* __restrict__ Bt,
                float* __restrict__ C, int M, int N, int Kd,
                float2* __restrict__ pst) {
    extern __shared__ u16 lds[];
    uint8_t* lds8 = (uint8_t*)lds;
    const int nx  = N >> 8;
    const int nwg = (M >> 8) * nx;
    int bid = blockIdx.x;
    int wg  = ((nwg & 7) == 0) ? ((bid & 7) * (nwg >> 3) + (bid >> 3)) : bid;
    const int bm = wg / nx, bn = wg % nx;
    const size_t brow = (size_t)bm << 8, bcol = (size_t)bn << 8;
    const int tid = threadIdx.x;
    const int l = tid & 63, wid = tid >> 6;
    const int wm = wid >> 2, wn = wid & 3;
    const int lr = l & 15, lq = l >> 4;
    const int sw = lr & 7;
    f32x4 acc[8][4] = {};
    const int arow = (wm * 128 + lr) * 128;     // byte offsets, 128B rows
    const int brow2 = (wn * 64 + lr) * 128;
    // lane's 32B fragment = blocks lq*2, lq*2+1, swizzled per row
    const int f0 = ((lq * 2 + 0) ^ sw) * 16;
    const int f1 = ((lq * 2 + 1) ^ sw) * 16;

    #pragma unroll
    for (int i = 0; i < 4; ++i) STAGE8(A,  brow, 0, i, 0);
    #pragma unroll
    for (int i = 0; i < 4; ++i) STAGE8(Bt, bcol, 0, i, 98304);
    #pragma unroll
    for (int i = 0; i < 4; ++i) STAGE8(A,  brow, 1, i, 32768);
    asm volatile("s_waitcnt vmcnt(4)" ::: "memory");
    __builtin_amdgcn_s_barrier();

    const int T = Kd >> 7;      // K-tiles of 128
    int abi = 0;
    #pragma unroll 1
    for (int t = 0; t < T; ++t) {
        const int aB = abi * 32768;
        const int bB = 98304 + (t & 1) * 32768;
        const int aN = (abi >= 1 ? abi - 1 : 2) * 32768;
        const int bN = 98304 + ((t + 1) & 1) * 32768;
        v8i a8[8], b8[4];
        #pragma unroll
        for (int mi = 0; mi < 8; ++mi)
            a8[mi] = ld_frag32(lds8 + aB + arow + mi * 2048 + f0,
                               lds8 + aB + arow + mi * 2048 + f1);
        #pragma unroll
        for (int ni = 0; ni < 4; ++ni)
            b8[ni] = ld_frag32(lds8 + bB + brow2 + ni * 2048 + f0,
                               lds8 + bB + brow2 + ni * 2048 + f1);
        if (t + 1 < T) {
            STAGE8(Bt, bcol, t + 1, 0, bN); STAGE8(Bt, bcol, t + 1, 1, bN);
            STAGE8(Bt, bcol, t + 1, 2, bN); STAGE8(Bt, bcol, t + 1, 3, bN);
        }
        if (t + 2 < T) {
            STAGE8(A, brow, t + 2, 0, aN); STAGE8(A, brow, t + 2, 1, aN);
            STAGE8(A, brow, t + 2, 2, aN); STAGE8(A, brow, t + 2, 3, aN);
        }
        #pragma unroll
        for (int mi = 0; mi < 8; ++mi) {
            #pragma unroll
            for (int ni = 0; ni < 4; ++ni)
                acc[mi][ni] = __builtin_amdgcn_mfma_scale_f32_16x16x128_f8f6f4(
                    a8[mi], b8[ni], acc[mi][ni],
                    0, 0,                      // cbsz=fp8, blgp=fp8
                    0, 0x7f7f7f7f,             // A scale: e8m0 1.0
                    0, 0x7f7f7f7f);            // B scale: e8m0 1.0
        }
        if (t < T - 2) { asm volatile("s_waitcnt vmcnt(4)" ::: "memory"); }
        else           { asm volatile("s_waitcnt vmcnt(0)" ::: "memory"); }
        __builtin_amdgcn_s_barrier();
        abi = (abi == 2) ? 0 : abi + 1;
    }

    // epilogue: per-m stats (native __expf) interleaved with C stores.
    float2* sbuf = (float2*)lds8;              // [256][5] float2, padded
    #pragma unroll
    for (int m = 0; m < 8; ++m) {
        #pragma unroll
        for (int rr = 0; rr < 4; ++rr) {
            float v0 = acc[m][0][rr], v1 = acc[m][1][rr];
            float v2 = acc[m][2][rr], v3 = acc[m][3][rr];
            float mx = fmaxf(fmaxf(v0, v1), fmaxf(v2, v3));
            #pragma unroll
            for (int o = 1; o < 16; o <<= 1) mx = fmaxf(mx, __shfl_xor(mx, o));
            float se = __expf(v0 - mx) + __expf(v1 - mx) + __expf(v2 - mx) + __expf(v3 - mx);
            #pragma unroll
            for (int o = 1; o < 16; o <<= 1) se += __shfl_xor(se, o);
            if (lr == 0) {
                const int rl = wm * 128 + m * 16 + lq * 4 + rr;
                sbuf[rl * 5 + wn] = make_float2(mx, se);
            }
        }
        const size_t rb = brow + wm * 128 + m * 16 + lq * 4;
        #pragma unroll
        for (int n = 0; n < 4; ++n) {
            const size_t cb = bcol + wn * 64 + n * 16 + lr;
            #pragma unroll
            for (int rr = 0; rr < 4; ++rr)
                C[(rb + rr) * (size_t)N + cb] = acc[m][n][rr];
        }
    }
    asm volatile("s_waitcnt lgkmcnt(0)" ::: "memory");
    __builtin_amdgcn_s_barrier();
    if (tid < 256) {
        const float2 p0 = sbuf[tid * 5 + 0], p1 = sbuf[tid * 5 + 1];
        const float2 p2 = sbuf[tid * 5 + 2], p3 = sbuf[tid * 5 + 3];
        const float M2 = fmaxf(fmaxf(p0.x, p1.x), fmaxf(p2.x, p3.x));
        const float S2 = p0.y * __expf(p0.x - M2) + p1.y * __expf(p1.x - M2)
                       + p2.y * __expf(p2.x - M2) + p3.y * __expf(p3.x - M2);
        pst[(brow + tid) * (N >> 8) + bn] = make_float2(M2, S2);
    }
}

// ---------------- final per-row loss from partials + diagonal ----------
__global__ __launch_bounds__(256)
void loss_final_k(const float2* __restrict__ pst, const float* __restrict__ logits,
                  float* __restrict__ peld, float* __restrict__ pelp) {
    const int tid = threadIdx.x;
    const int wv = tid >> 6, half = (tid & 63) >> 5, l5 = tid & 31;
    const int row = blockIdx.x * 8 + wv * 2 + half;
    const float2 p = pst[(size_t)row * 32 + l5];
    const float d = logits[(size_t)row * (KSEL + 1)];   // diagonal
    float M = p.x;
    #pragma unroll
    for (int o = 1; o < 32; o <<= 1) M = fmaxf(M, __shfl_xor(M, o));
    float S = p.y * __expf(p.x - M);
    #pragma unroll
    for (int o = 1; o < 32; o <<= 1) S += __shfl_xor(S, o);
    if (l5 == 0) {
        const float pi = __expf(d - M) / S;
        peld[row] = 2.0f - 2.0f * pi + (float)(KSEL - 2) * PD_EPS;
        pelp[row] = M + __logf(S) - d;
    }
}

// ---------------- block reduce helpers ----------------
__device__ inline float blockSum(float v, float* red) {
    #pragma unroll
    for (int o = 32; o > 0; o >>= 1) v += __shfl_down(v, o);
    __syncthreads();
    if ((threadIdx.x & 63) == 0) red[threadIdx.x >> 6] = v;
    __syncthreads();
    return red[0] + red[1] + red[2] + red[3];
}

// ------- bias + LayerNorm (sum of 2 split-K planes) -> fp8 ----------
__global__ void ln_k(const float* __restrict__ Hp0, const float* __restrict__ Hp1,
                     const float* __restrict__ bias,
                     const float* __restrict__ gamma, const float* __restrict__ beta,
                     uint8_t* __restrict__ Hb8) {
    __shared__ float red[4];
    const int r = blockIdx.x, t = threadIdx.x;
    float4 x4 = *(const float4*)(Hp0 + (size_t)r * HD + t * 4);
    float4 y4 = *(const float4*)(Hp1 + (size_t)r * HD + t * 4);
    float4 b4 = *(const float4*)(bias + t * 4);
    float x[4] = { x4.x + y4.x + b4.x, x4.y + y4.y + b4.y,
                   x4.z + y4.z + b4.z, x4.w + y4.w + b4.w };
    float s = x[0] + x[1] + x[2] + x[3];
    float mu = blockSum(s, red) * (1.0f / HD);
    float d0 = x[0] - mu, d1 = x[1] - mu, d2 = x[2] - mu, d3 = x[3] - mu;
    float vs = d0 * d0 + d1 * d1 + d2 * d2 + d3 * d3;
    float var = blockSum(vs, red) * (1.0f / HD);
    float rs = rsqrtf(var + LN_EPS);
    float4 g4 = *(const float4*)(gamma + t * 4);
    float4 e4 = *(const float4*)(beta + t * 4);
    float y0 = d0 * rs * g4.x + e4.x;
    float y1 = d1 * rs * g4.y + e4.y;
    float y2 = d2 * rs * g4.z + e4.z;
    float y3 = d3 * rs * g4.w + e4.w;
    *(uint32_t*)(Hb8 + (size_t)r * HD + t * 4) = pack4_f8(y0, y1, y2, y3);
}

// ---------------- deterministic two-stage f64 reduction ----------------
__global__ __launch_bounds__(1024)
void reduce_k(const float* __restrict__ peld, const float* __restrict__ pelp,
              float* __restrict__ scalars) {
    __shared__ double red[4][16];
    const int t = threadIdx.x;
    double a = 0.0, b = 0.0, c = 0.0, d = 0.0;
    for (int i = t; i < KSEL; i += 1024) {
        const double pd = (double)peld[i];
        const double pp = (double)pelp[i];
        a += pd; b += pd * pd; c += pp; d += pp * pp;
    }
    #pragma unroll
    for (int o = 32; o > 0; o >>= 1) {
        a += __shfl_down(a, o); b += __shfl_down(b, o);
        c += __shfl_down(c, o); d += __shfl_down(d, o);
    }
    const int wv = t >> 6;
    if ((t & 63) == 0) { red[0][wv] = a; red[1][wv] = b; red[2][wv] = c; red[3][wv] = d; }
    __syncthreads();
    if (t == 0) {
        double s1 = 0, s2 = 0, s3 = 0, s4 = 0;
        #pragma unroll
        for (int i = 0; i < 16; ++i) { s1 += red[0][i]; s2 += red[1][i]; s3 += red[2][i]; s4 += red[3][i]; }
        const double Kd = (double)KSEL;
        const double denom = Kd + 1e-5;
        scalars[0] = (float)(s1 / denom);
        scalars[1] = (float)(s3 / denom);
        scalars[2] = (float)((s2 - s1 * s1 / Kd) / (Kd - 1.0));
        scalars[3] = (float)((s4 - s3 * s3 / Kd) / (Kd - 1.0));
    }
}

extern "C" void kernel_launch(void* const* d_in, const int* in_sizes, int n_in,
                              void* d_out, int out_size, void* d_ws, size_t ws_size,
                              hipStream_t stream) {
    const float* msp   = (const float*)d_in[0];
    const float* lab   = (const float*)d_in[1];
    const void*  mask  = d_in[2];
    const float* W     = (const float*)d_in[3];
    const float* bias  = (const float*)d_in[4];
    const float* gamma = (const float*)d_in[5];
    const float* beta  = (const float*)d_in[6];
    float* out = (float*)d_out;
    char*  ws  = (char*)d_ws;

    int*     idx      = (int*)ws;                         // 32 KB
    float2*  pst      = (float2*)(ws + 65536);            // 2 MB, reuses wBf after GEMM1
    u16*     wBf      = (u16*)(ws + 65536);               // 2 MB
    uint8_t* labelsB8 = (uint8_t*)(ws + (size_t)(4  << 20)); // 8 MB
    uint8_t* hB8      = (uint8_t*)(ws + (size_t)(20 << 20)); // 8 MB
    u16*     predsB   = (u16*)d_out;                      // 16 MB scratch (dead before GEMM2)
    float*   hPre     = out + ((size_t)8 << 20);          // 2 planes x 32 MB (dead before GEMM2)

    float* peld    = out + (size_t)KSEL * KSEL;
    float* pelp    = peld + KSEL;
    float* scalars = pelp + KSEL;

    hipFuncSetAttribute(reinterpret_cast<const void*>(&gemm256a_k),
                        hipFuncAttributeMaxDynamicSharedMemorySize, 163840);
    hipFuncSetAttribute(reinterpret_cast<const void*>(&gemm256s_k),
                        hipFuncAttributeMaxDynamicSharedMemorySize, 163840);

    compact_mask_k<<<1, 1024, 0, stream>>>((const uint8_t*)mask, (const int32_t*)mask, idx);
    gather_conv_k<<<KSEL + 1024, 256, 0, stream>>>(msp, lab, idx, W, predsB, labelsB8, wBf);
    gemm256a_k<<<2 * (KSEL / 256) * (HD / 256), 512, 163840, stream>>>(
        predsB, wBf, hPre, KSEL, HD, HD);
    ln_k<<<KSEL, 256, 0, stream>>>(hPre, hPre + (size_t)KSEL * HD, bias, gamma, beta, hB8);
    gemm256s_k<<<(KSEL / 256) * (KSEL / 256), 512, 163840, stream>>>(
        hB8, labelsB8, out, KSEL, KSEL, HD, pst);
    loss_final_k<<<KSEL / 8, 256, 0, stream>>>(pst, out, peld, pelp);
    reduce_k<<<1, 1024, 0, stream>>>(peld, pelp, scalars);
}